// Round 7
// baseline (1122.876 us; speedup 1.0000x reference)
//
#include <hip/hip_runtime.h>
#include <math.h>

// NaryTreeLSTM on MI355X — round 17: fused per-level kernel for d<=11.
// R16 post-mortem: assignable kernel time ~480us vs 794 measured — ~300us is
// the serial launch chain (36 dependent launches, tiny latency-bound tail).
// Fix: fused_level = one launch per level d=11..0. Block = 16 rows x 1280
// cols, no LDS/barriers: A-frags from row-major Zrow (L2-hot), B-frags from
// frag-major Wfrag (L2), wave owns all 5 gates for its 64 h-cols (20 MFMA
// tiles), LSTM epilogue fused in-registers (c, h, hsum -> parent z).
// Kills 12 launches + G round-trip for d<=11 + the 10-launch tail.
// Proven path kept: gate_gemm_big (leaf, d>=13), 128^2 gemm (d=12),
// combine_v. cvt_all now writes ALL internal levels row-major into Zrow.

#define LEAF_N 65536

typedef __attribute__((ext_vector_type(8))) short bf16x8;
typedef __attribute__((ext_vector_type(4))) float f32x4;
typedef __attribute__((ext_vector_type(8))) float f32x8;
typedef __attribute__((ext_vector_type(8))) _Float16 f16x8;
typedef unsigned short u16;

__device__ __forceinline__ float fast_sig(float x) {
    return __builtin_amdgcn_rcpf(1.0f + __expf(-x));
}
__device__ __forceinline__ float fast_tanh(float x) {
    return 2.0f * __builtin_amdgcn_rcpf(1.0f + __expf(-2.0f * x)) - 1.0f;
}

__device__ __forceinline__ u16 f2bf(float f) {
    union { float f; unsigned u; } v; v.f = f;
    unsigned r = v.u + 0x7fffu + ((v.u >> 16) & 1u);   // RNE
    return (u16)(r >> 16);
}

// row-major Z offset (elems) for level d in [0,15]; levels are contiguous.
__host__ __device__ __forceinline__ size_t zrowOff(int d) {
    return (size_t)(65536 - (2 << d)) * 512;
}

__device__ __forceinline__ void gld_lds16(const u16* g, u16* s) {
    __builtin_amdgcn_global_load_lds(
        (const __attribute__((address_space(1))) void*)g,
        (__attribute__((address_space(3))) void*)s, 16, 0, 0);
}

// ---------------- weight packing ----------------
// Wrow: row-major 1280x512 ([i|Ui],[o|Uo],[u|Uu],[f|Wfk0],[f|Wfk1])
// Wfrag: frag-major same matrix (fused_level):
//   addr = ((nt*16+kc)*64 + l)*8 + j ; row=nt*16+(l&15), k=kc*32+(l>>4)*8+j
// WleafRow: row-major 768x256 ([i;o;u])
__global__ __launch_bounds__(256) void pack_weights(
    const float* __restrict__ Wi, const float* __restrict__ bi,
    const float* __restrict__ Wf, const float* __restrict__ bf,
    const float* __restrict__ Wo, const float* __restrict__ bo,
    const float* __restrict__ Wu, const float* __restrict__ bu,
    const float* __restrict__ Ui, const float* __restrict__ Uo,
    const float* __restrict__ Uu, const float* __restrict__ Wfk,
    u16* __restrict__ Wrow, u16* __restrict__ Wfrag, u16* __restrict__ WleafRow,
    float* __restrict__ bbig, float* __restrict__ bleaf)
{
    int idx = blockIdx.x * 256 + threadIdx.x;
    const int NWB = 1280 * 512;
    const int NWL = 768 * 256;

    auto bigval = [&](int row, int k) -> float {
        int g = row >> 8, rr = row & 255;
        if (k < 256) {
            const float* W = (g == 0) ? Wi : (g == 1) ? Wo : (g == 2) ? Wu : Wf;
            return W[rr * 256 + k];
        }
        int kk = k - 256;
        return (g == 0) ? Ui[rr * 256 + kk]
             : (g == 1) ? Uo[rr * 256 + kk]
             : (g == 2) ? Uu[rr * 256 + kk]
             : (g == 3) ? Wfk[rr * 256 + kk]
                        : Wfk[65536 + rr * 256 + kk];
    };

    if (idx < NWB) {
        Wrow[idx] = f2bf(bigval(idx >> 9, idx & 511));
    } else if (idx < 2 * NWB) {
        int q = idx - NWB;
        int j = q & 7, l = (q >> 3) & 63, kc = (q >> 9) & 15, nt = q >> 13;
        int row = nt * 16 + (l & 15);
        int k = kc * 32 + ((l >> 4) << 3) + j;
        Wfrag[q] = f2bf(bigval(row, k));
    } else if (idx < 2 * NWB + NWL) {
        int q = idx - 2 * NWB;
        int r = q >> 8, k = q & 255;
        int g = r >> 8, rr = r & 255;
        const float* W = (g == 0) ? Wi : (g == 1) ? Wo : Wu;
        WleafRow[q] = f2bf(W[rr * 256 + k]);
    } else if (idx < 2 * NWB + NWL + 1280) {
        int r = idx - 2 * NWB - NWL;
        int g = r >> 8, rr = r & 255;
        bbig[r] = (g == 0) ? bi[rr] : (g == 1) ? bo[rr] : (g == 2) ? bu[rr] : bf[rr];
    } else if (idx < 2 * NWB + NWL + 1280 + 768) {
        int r = idx - 2 * NWB - NWL - 1280;
        int g = r >> 8, rr = r & 255;
        bleaf[r] = (g == 0) ? bi[rr] : (g == 1) ? bo[rr] : bu[rr];
    }
}

// ---------------- x -> bf16 conversion ----------------
// internal rows (all levels 0..15): row-major Zrow; leaves: Xbf.
__global__ __launch_bounds__(256) void cvt_all(
    const float* __restrict__ x, u16* __restrict__ Zrow,
    u16* __restrict__ Xbf)
{
    int idx = blockIdx.x * 256 + threadIdx.x;
    if (idx >= 131071 * 32) return;
    int row = idx >> 5, k8 = idx & 31;
    const float* s = x + (size_t)row * 256 + k8 * 8;
    u16 r[8];
#pragma unroll
    for (int i = 0; i < 8; i++) r[i] = f2bf(s[i]);
    if (row < 65535) {
        int d = 31 - __clz(row + 1);
        int jn = row - ((1 << d) - 1);
        *(uint4*)(Zrow + zrowOff(d) + (size_t)jn * 512 + k8 * 8) = *(uint4*)r;
    } else {
        int jn = row - 65535;
        *(uint4*)(Xbf + (size_t)jn * 256 + k8 * 8) = *(uint4*)r;
    }
}

// ---------------- stage 1a: big-level GEMM (256x256, dbuf 2-phase) --------
template<int KD, int NC>
__global__ __launch_bounds__(512, 2) void gate_gemm_big(
    const u16* __restrict__ A, const u16* __restrict__ B,
    const float* __restrict__ bias, _Float16* __restrict__ G)
{
    constexpr int NT = KD / 64;
    extern __shared__ u16 S[];           // [2][A:16384 | B:16384]

    const int tid  = threadIdx.x;
    const int wave = tid >> 6;
    const int lane = tid & 63;
    const int bm = blockIdx.x * 256;
    const int bn = blockIdx.y * 256;

    const int srow = lane >> 3;
    const int scol = ((lane & 7) ^ srow) * 8;

    const int wr = wave >> 2;
    const int wc = wave & 3;
    const int lm = lane & 15, q4 = lane >> 4;

    auto stage = [&](int bi, int t) {
#pragma unroll
        for (int q = 0; q < 4; ++q) {
            const int g = wave * 4 + q;
            const int r = g * 8 + srow;
            gld_lds16(A + (size_t)(bm + r) * KD + t * 64 + scol,
                      S + bi * 32768 + g * 512 + lane * 8);
            gld_lds16(B + (size_t)(bn + r) * KD + t * 64 + scol,
                      S + bi * 32768 + 16384 + g * 512 + lane * 8);
        }
    };

    f32x4 acc[8][4] = {};

    stage(0, 0);
    __syncthreads();

#pragma unroll
    for (int t = 0; t < NT; ++t) {
        if (t + 1 < NT) stage((t + 1) & 1, t + 1);

        const u16* Ab = S + (t & 1) * 32768;
        const u16* Bb = Ab + 16384;
#pragma unroll
        for (int kk = 0; kk < 64; kk += 32) {
            const int sw = ((((kk >> 3) + q4) ^ (lm & 7)) << 3);
            bf16x8 af[8], bfr[4];
#pragma unroll
            for (int i = 0; i < 8; i++)
                af[i] = *(const bf16x8*)(Ab + (wr * 128 + i * 16 + lm) * 64 + sw);
#pragma unroll
            for (int j = 0; j < 4; j++)
                bfr[j] = *(const bf16x8*)(Bb + (wc * 64 + j * 16 + lm) * 64 + sw);
#pragma unroll
            for (int i = 0; i < 8; i++)
#pragma unroll
                for (int j = 0; j < 4; j++)
                    acc[i][j] = __builtin_amdgcn_mfma_f32_16x16x32_bf16(
                        af[i], bfr[j], acc[i][j], 0, 0, 0);
        }
        __syncthreads();
    }

    const int cr0 = q4 * 4;
#pragma unroll
    for (int i = 0; i < 8; i++) {
#pragma unroll
        for (int j = 0; j < 4; j++) {
            const int cg = bn + wc * 64 + j * 16 + lm;
            const float bb = bias[cg];
            const bool istan = ((cg >> 8) == 2);
#pragma unroll
            for (int reg = 0; reg < 4; reg++) {
                const int rr = bm + wr * 128 + i * 16 + cr0 + reg;
                float v = acc[i][j][reg] + bb;
                G[(size_t)rr * NC + cg] =
                    (_Float16)(istan ? fast_tanh(v) : fast_sig(v));
            }
        }
    }
}

// ---------------- stage 1b: 128x128 gate GEMM (d=12) -----------
__global__ __launch_bounds__(256) void gate_gemm(
    const u16* __restrict__ A, int lda, int M,
    const u16* __restrict__ B, int ldb, int Kdim,
    const float* __restrict__ bias, _Float16* __restrict__ G, int NC)
{
    __shared__ u16 As[128 * 64];
    __shared__ u16 Bs[128 * 64];

    const int tid  = threadIdx.x;
    const int wave = tid >> 6;
    const int lane = tid & 63;
    const int bm = blockIdx.x * 128;
    const int bn = blockIdx.y * 128;

    const int wm = (wave >> 1) * 64;
    const int wn = (wave & 1) * 64;
    const int lm = lane & 15;
    const int q4 = lane >> 4;

    const int srow = lane >> 3;
    const int scol = ((lane & 7) ^ srow) * 8;

    f32x4 acc[4][4] = {};

    for (int k0 = 0; k0 < Kdim; k0 += 64) {
#pragma unroll
        for (int q = 0; q < 4; ++q) {
            const int grp = wave * 4 + q;
            const int r = grp * 8 + srow;
            gld_lds16(A + (size_t)(bm + r) * lda + k0 + scol,
                      As + (size_t)grp * 512 + lane * 8);
            gld_lds16(B + (size_t)(bn + r) * ldb + k0 + scol,
                      Bs + (size_t)grp * 512 + lane * 8);
        }
        __syncthreads();

#pragma unroll
        for (int kk = 0; kk < 64; kk += 32) {
            const int sw = (((kk >> 3) + q4) ^ (lm & 7)) << 3;
            bf16x8 af[4], bfr[4];
#pragma unroll
            for (int i = 0; i < 4; i++)
                af[i] = *(const bf16x8*)(As + (wm + i * 16 + lm) * 64 + sw);
#pragma unroll
            for (int j = 0; j < 4; j++)
                bfr[j] = *(const bf16x8*)(Bs + (wn + j * 16 + lm) * 64 + sw);
#pragma unroll
            for (int i = 0; i < 4; i++)
#pragma unroll
                for (int j = 0; j < 4; j++)
                    acc[i][j] = __builtin_amdgcn_mfma_f32_16x16x32_bf16(
                        af[i], bfr[j], acc[i][j], 0, 0, 0);
        }
        __syncthreads();
    }

    const int cr0 = q4 * 4;
    const int ccc = lm;
#pragma unroll
    for (int i = 0; i < 4; i++) {
#pragma unroll
        for (int reg = 0; reg < 4; reg++) {
            int r = bm + wm + i * 16 + cr0 + reg;
            if (r >= M) continue;
#pragma unroll
            for (int j = 0; j < 4; j++) {
                int cn = bn + wn + j * 16 + ccc;
                float v = acc[i][j][reg] + bias[cn];
                float a = ((cn >> 8) == 2) ? fast_tanh(v) : fast_sig(v);
                G[(size_t)r * NC + cn] = (_Float16)a;
            }
        }
    }
}

// ---------------- stage 2: vectorized combine (z row-major always) --------
template<bool LEAF>
__global__ __launch_bounds__(256) void combine_v(
    const _Float16* __restrict__ G, const float* __restrict__ csrc,
    float* __restrict__ cdst, u16* __restrict__ zrow_parent)
{
    constexpr int NC = LEAF ? 768 : 1280;
    const int t  = threadIdx.x;
    const int p  = blockIdx.x * 8 + (t >> 5);      // global pair index
    const int h0 = (t & 31) * 8;

    const _Float16* G0 = G + (size_t)(2 * p) * NC + h0;
    const _Float16* G1 = G0 + NC;

    f16x8 i0 = *(const f16x8*)(G0);
    f16x8 o0 = *(const f16x8*)(G0 + 256);
    f16x8 u0 = *(const f16x8*)(G0 + 512);
    f16x8 i1 = *(const f16x8*)(G1);
    f16x8 o1 = *(const f16x8*)(G1 + 256);
    f16x8 u1 = *(const f16x8*)(G1 + 512);

    f32x8 c0, c1;
#pragma unroll
    for (int e = 0; e < 8; e++) {
        c0[e] = (float)i0[e] * (float)u0[e];
        c1[e] = (float)i1[e] * (float)u1[e];
    }
    if (!LEAF) {
        f16x8 f00 = *(const f16x8*)(G0 + 768);
        f16x8 f10 = *(const f16x8*)(G0 + 1024);
        f16x8 f01 = *(const f16x8*)(G1 + 768);
        f16x8 f11 = *(const f16x8*)(G1 + 1024);
        const float* cs = csrc + (size_t)(4 * p) * 256 + h0;
        f32x8 cc0 = *(const f32x8*)(cs);
        f32x8 cc1 = *(const f32x8*)(cs + 256);
        f32x8 cc2 = *(const f32x8*)(cs + 512);
        f32x8 cc3 = *(const f32x8*)(cs + 768);
#pragma unroll
        for (int e = 0; e < 8; e++) {
            c0[e] += (float)f00[e] * cc0[e] + (float)f10[e] * cc1[e];
            c1[e] += (float)f01[e] * cc2[e] + (float)f11[e] * cc3[e];
        }
    }

    u16 hs[8];
#pragma unroll
    for (int e = 0; e < 8; e++) {
        float h0v = (float)o0[e] * fast_tanh(c0[e]);
        float h1v = (float)o1[e] * fast_tanh(c1[e]);
        hs[e] = f2bf(h0v + h1v);
    }

    float* cd = cdst + (size_t)(2 * p) * 256 + h0;
    *(f32x8*)(cd) = c0;
    *(f32x8*)(cd + 256) = c1;

    *(uint4*)(zrow_parent + (size_t)p * 512 + 256 + h0) = *(uint4*)hs;
}

// ---------------- fused per-level kernel (d<=11) ----------------
// Block: 16 rows x 1280 cols, 4 waves; wave w owns h-cols [w*64,w*64+64)
// for ALL 5 gates (20 MFMA col-tiles). A-frags direct from row-major Zrow,
// B-frags direct from frag-major Wfrag. No LDS, no barriers.
// Epilogue in-registers: c = sig(i)*tanh(u) + sig(f0)*c2r + sig(f1)*c2r1;
// h = sig(o)*tanh(c); hsum per sibling pair -> parent z (row-major h-part).
// Root (out != nullptr): out = [h(256) | c(256)] of row 0.
__global__ __launch_bounds__(256) void fused_level(
    const u16* __restrict__ Z, const u16* __restrict__ Wfrag,
    const float* __restrict__ bbig, const float* __restrict__ csrc,
    float* __restrict__ cdst, u16* __restrict__ zp,
    float* __restrict__ out, int n)
{
    const int lane = threadIdx.x & 63;
    const int w = threadIdx.x >> 6;
    const int r0 = blockIdx.x * 16;
    const int cc = lane & 15, rq = (lane >> 4) * 4;

    f32x4 acc[5][4] = {};                       // [gate][jt]

    const int arow = min(r0 + cc, n - 1);       // clamped A row (pads dup)
    const u16* aB = Z + (size_t)arow * 512 + (lane >> 4) * 8;

#pragma unroll 2
    for (int kc = 0; kc < 16; ++kc) {
        bf16x8 av = *(const bf16x8*)(aB + kc * 32);
#pragma unroll
        for (int g = 0; g < 5; ++g)
#pragma unroll
            for (int jt = 0; jt < 4; ++jt) {
                const int nt = g * 16 + w * 4 + jt;
                bf16x8 bv = *(const bf16x8*)(Wfrag +
                    ((size_t)(nt * 16 + kc) * 64 + lane) * 8);
                acc[g][jt] = __builtin_amdgcn_mfma_f32_16x16x32_bf16(
                    av, bv, acc[g][jt], 0, 0, 0);
            }
    }

#pragma unroll
    for (int jt = 0; jt < 4; ++jt) {
        const int h = (w * 4 + jt) * 16 + cc;
        const float bI = bbig[h],        bO = bbig[256 + h];
        const float bU = bbig[512 + h],  bF0 = bbig[768 + h];
        const float bF1 = bbig[1024 + h];
        float cr[4], hr[4];
#pragma unroll
        for (int r = 0; r < 4; ++r) {
            const int row = r0 + rq + r;
            float cv = 0.f, hv = 0.f;
            if (row < n) {
                float i  = fast_sig(acc[0][jt][r] + bI);
                float o  = fast_sig(acc[1][jt][r] + bO);
                float u  = fast_tanh(acc[2][jt][r] + bU);
                float f0 = fast_sig(acc[3][jt][r] + bF0);
                float f1 = fast_sig(acc[4][jt][r] + bF1);
                cv = i * u
                   + f0 * csrc[(size_t)(2 * row) * 256 + h]
                   + f1 * csrc[(size_t)(2 * row + 1) * 256 + h];
                hv = o * fast_tanh(cv);
            }
            cr[r] = cv; hr[r] = hv;
        }
        if (out) {
            if (rq == 0) { out[h] = hr[0]; out[256 + h] = cr[0]; }
        } else {
#pragma unroll
            for (int r = 0; r < 4; ++r) {
                const int row = r0 + rq + r;
                if (row < n) cdst[(size_t)row * 256 + h] = cr[r];
            }
#pragma unroll
            for (int s = 0; s < 2; ++s) {
                const int row = r0 + rq + 2 * s;
                if (row < n) {
                    const int pp = row >> 1;
                    zp[(size_t)pp * 512 + 256 + h] = f2bf(hr[2 * s] + hr[2 * s + 1]);
                }
            }
        }
    }
}

// ---------------- launch ----------------
extern "C" void kernel_launch(void* const* d_in, const int* in_sizes, int n_in,
                              void* d_out, int out_size, void* d_ws, size_t ws_size,
                              hipStream_t stream)
{
    const float* x   = (const float*)d_in[0];
    const float* Wi  = (const float*)d_in[1];
    const float* bi  = (const float*)d_in[2];
    const float* Wf  = (const float*)d_in[3];
    const float* bf  = (const float*)d_in[4];
    const float* Wo  = (const float*)d_in[5];
    const float* bo  = (const float*)d_in[6];
    const float* Wu  = (const float*)d_in[7];
    const float* bu  = (const float*)d_in[8];
    const float* Ui  = (const float*)d_in[9];
    const float* Uo  = (const float*)d_in[10];
    const float* Uu  = (const float*)d_in[11];
    const float* Wfk = (const float*)d_in[12];
    float* out = (float*)d_out;
    char* ws   = (char*)d_ws;
    (void)ws_size; (void)in_sizes; (void)n_in; (void)out_size;

    size_t off = 0;
    u16* Wrow     = (u16*)(ws + off); off += (size_t)1280 * 512 * 2;
    u16* Wfrag    = (u16*)(ws + off); off += (size_t)1280 * 512 * 2;
    u16* WleafRow = (u16*)(ws + off); off += (size_t)768 * 256 * 2;
    float* bbig   = (float*)(ws + off); off += 1280 * 4;
    float* bleaf  = (float*)(ws + off); off += 768 * 4 + 192;                // 256B align
    u16* Xbf    = (u16*)(ws + off); off += (size_t)65536 * 256 * 2;          // 32 MB
    u16* Zrow   = (u16*)(ws + off); off += (size_t)65536 * 512 * 2;          // 64 MB
    float* cA = (float*)(ws + off); off += (size_t)65536 * 256 * 4;          // 64 MB
    float* cB = (float*)(ws + off); off += (size_t)32768 * 256 * 4;          // 32 MB
    _Float16* Ghalf = (_Float16*)(ws + off); off += (size_t)65536 * 768 * 2; // 96 MB

    // allow 128KB dynamic LDS for the big gemm (host-side, idempotent)
    static bool attr_set = false;
    if (!attr_set) {
        hipFuncSetAttribute((const void*)gate_gemm_big<512, 1280>,
                            hipFuncAttributeMaxDynamicSharedMemorySize, 131072);
        hipFuncSetAttribute((const void*)gate_gemm_big<256, 768>,
                            hipFuncAttributeMaxDynamicSharedMemorySize, 131072);
        attr_set = true;
    }

    // 1) pack weights + convert x
    pack_weights<<<5897, 256, 0, stream>>>(Wi, bi, Wf, bf, Wo, bo, Wu, bu,
                                           Ui, Uo, Uu, Wfk, Wrow, Wfrag, WleafRow,
                                           bbig, bleaf);
    cvt_all<<<16385, 256, 0, stream>>>(x, Zrow, Xbf);

    // 2) leaf: gemm (i,o,u fp16) + combine -> cA, Hs into Zrow level 15
    gate_gemm_big<256, 768><<<dim3(LEAF_N / 256, 3), 512, 131072, stream>>>(
        Xbf, WleafRow, bleaf, Ghalf);
    combine_v<true><<<LEAF_N / 16, 256, 0, stream>>>(
        Ghalf, nullptr, cA, Zrow + zrowOff(15));

    // 3) big internal levels d=15..12
    for (int d = 15; d >= 12; d--) {
        int n = 1 << d;
        float* csrc = (d & 1) ? cA : cB;
        float* cdst = (d & 1) ? cB : cA;
        if (d >= 13) {
            gate_gemm_big<512, 1280><<<dim3(n / 256, 5), 512, 131072, stream>>>(
                Zrow + zrowOff(d), Wrow, bbig, Ghalf);
        } else {
            gate_gemm<<<dim3(n / 128, 10), 256, 0, stream>>>(
                Zrow + zrowOff(d), 512, n, Wrow, 512, 512, bbig, Ghalf, 1280);
        }
        combine_v<false><<<n / 16, 256, 0, stream>>>(
            Ghalf, csrc, cdst, Zrow + zrowOff(d - 1));
    }

    // 4) fused levels d=11..1
    for (int d = 11; d >= 1; d--) {
        int n = 1 << d;
        float* csrc = (d & 1) ? cA : cB;
        float* cdst = (d & 1) ? cB : cA;
        int blocks = (n + 15) / 16;
        fused_level<<<blocks, 256, 0, stream>>>(
            Zrow + zrowOff(d), Wfrag, bbig, csrc, cdst,
            Zrow + zrowOff(d - 1), nullptr, n);
    }

    // 5) root (d=0): out = [h(256) | c(256)]
    fused_level<<<1, 256, 0, stream>>>(
        Zrow + zrowOff(0), Wfrag, bbig, cB, nullptr, nullptr, out, 1);
}

// Round 8
// 1065.663 us; speedup vs baseline: 1.0537x; 1.0537x over previous
//
#include <hip/hip_runtime.h>
#include <math.h>

// NaryTreeLSTM on MI355X — round 18: persistent lower-tree kernel.
// R17 post-mortem: fused_level had every block read ALL of Wfrag (168MB/level,
// HBM-refetched per dispatch, latency-bound) -> 126us/level. But it proved the
// R16 gap: streaming combines evict weights from L2 between dispatches, so
// every small dispatch pays ~10MB HBM refetch + launch gap (~300us total).
// R18: upper pipeline = R16 verbatim (leaf + d=15..12 big gemm + combine_v).
// Lower tree d=11..0 = ONE persistent kernel (80 blocks, co-resident, no LDS):
// per level {gemm phase: R0-proven 1-wave units of 16 rows x 4 col-tiles,
// each reading only its 64KB Wfrag slice (L2-resident across all levels)} ->
// device-scope atomic grid barrier -> {vectorized combine epilogue} -> barrier.
// Kills ~26 launches + all inter-dispatch weight refetch.

#define LEAF_N 65536
#define NBLK 80

typedef __attribute__((ext_vector_type(8))) short bf16x8;
typedef __attribute__((ext_vector_type(4))) float f32x4;
typedef __attribute__((ext_vector_type(8))) float f32x8;
typedef __attribute__((ext_vector_type(8))) _Float16 f16x8;
typedef unsigned short u16;

__device__ __forceinline__ float fast_sig(float x) {
    return __builtin_amdgcn_rcpf(1.0f + __expf(-x));
}
__device__ __forceinline__ float fast_tanh(float x) {
    return 2.0f * __builtin_amdgcn_rcpf(1.0f + __expf(-2.0f * x)) - 1.0f;
}

__device__ __forceinline__ u16 f2bf(float f) {
    union { float f; unsigned u; } v; v.f = f;
    unsigned r = v.u + 0x7fffu + ((v.u >> 16) & 1u);   // RNE
    return (u16)(r >> 16);
}

// row-major Z offset (elems) for level d in [0,15]; levels are contiguous.
__host__ __device__ __forceinline__ size_t zrowOff(int d) {
    return (size_t)(65536 - (2 << d)) * 512;
}

__device__ __forceinline__ void gld_lds16(const u16* g, u16* s) {
    __builtin_amdgcn_global_load_lds(
        (const __attribute__((address_space(1))) void*)g,
        (__attribute__((address_space(3))) void*)s, 16, 0, 0);
}

// device-scope grid barrier (cooperative-groups pattern; 80 co-resident blocks)
__device__ __forceinline__ void gbar(unsigned* cnt, unsigned& ph) {
    __syncthreads();
    ++ph;
    if (threadIdx.x == 0) {
        __threadfence();
        __hip_atomic_fetch_add(cnt, 1u, __ATOMIC_ACQ_REL, __HIP_MEMORY_SCOPE_AGENT);
        const unsigned tgt = ph * NBLK;
        while (__hip_atomic_load(cnt, __ATOMIC_ACQUIRE,
                                 __HIP_MEMORY_SCOPE_AGENT) < tgt)
            __builtin_amdgcn_s_sleep(1);
    }
    __syncthreads();
    __threadfence();
}

// ---------------- weight packing ----------------
// Wrow: row-major 1280x512 ([i|Ui],[o|Uo],[u|Uu],[f|Wfk0],[f|Wfk1])
// Wfrag: frag-major same matrix (lower_levels gemm):
//   addr = ((nt*16+kc)*64 + l)*8 + j ; row=nt*16+(l&15), k=kc*32+(l>>4)*8+j
// WleafRow: row-major 768x256 ([i;o;u])
__global__ __launch_bounds__(256) void pack_weights(
    const float* __restrict__ Wi, const float* __restrict__ bi,
    const float* __restrict__ Wf, const float* __restrict__ bf,
    const float* __restrict__ Wo, const float* __restrict__ bo,
    const float* __restrict__ Wu, const float* __restrict__ bu,
    const float* __restrict__ Ui, const float* __restrict__ Uo,
    const float* __restrict__ Uu, const float* __restrict__ Wfk,
    u16* __restrict__ Wrow, u16* __restrict__ Wfrag, u16* __restrict__ WleafRow,
    float* __restrict__ bbig, float* __restrict__ bleaf,
    unsigned* __restrict__ barcnt)
{
    int idx = blockIdx.x * 256 + threadIdx.x;
    const int NWB = 1280 * 512;
    const int NWL = 768 * 256;

    auto bigval = [&](int row, int k) -> float {
        int g = row >> 8, rr = row & 255;
        if (k < 256) {
            const float* W = (g == 0) ? Wi : (g == 1) ? Wo : (g == 2) ? Wu : Wf;
            return W[rr * 256 + k];
        }
        int kk = k - 256;
        return (g == 0) ? Ui[rr * 256 + kk]
             : (g == 1) ? Uo[rr * 256 + kk]
             : (g == 2) ? Uu[rr * 256 + kk]
             : (g == 3) ? Wfk[rr * 256 + kk]
                        : Wfk[65536 + rr * 256 + kk];
    };

    if (idx < NWB) {
        Wrow[idx] = f2bf(bigval(idx >> 9, idx & 511));
    } else if (idx < 2 * NWB) {
        int q = idx - NWB;
        int j = q & 7, l = (q >> 3) & 63, kc = (q >> 9) & 15, nt = q >> 13;
        int row = nt * 16 + (l & 15);
        int k = kc * 32 + ((l >> 4) << 3) + j;
        Wfrag[q] = f2bf(bigval(row, k));
    } else if (idx < 2 * NWB + NWL) {
        int q = idx - 2 * NWB;
        int r = q >> 8, k = q & 255;
        int g = r >> 8, rr = r & 255;
        const float* W = (g == 0) ? Wi : (g == 1) ? Wo : Wu;
        WleafRow[q] = f2bf(W[rr * 256 + k]);
    } else if (idx < 2 * NWB + NWL + 1280) {
        int r = idx - 2 * NWB - NWL;
        int g = r >> 8, rr = r & 255;
        bbig[r] = (g == 0) ? bi[rr] : (g == 1) ? bo[rr] : (g == 2) ? bu[rr] : bf[rr];
    } else if (idx < 2 * NWB + NWL + 1280 + 768) {
        int r = idx - 2 * NWB - NWL - 1280;
        int g = r >> 8, rr = r & 255;
        bleaf[r] = (g == 0) ? bi[rr] : (g == 1) ? bo[rr] : bu[rr];
    } else if (idx == 2 * NWB + NWL + 1280 + 768) {
        *barcnt = 0u;                       // reset persistent-kernel barrier
    }
}

// ---------------- x -> bf16 conversion ----------------
// internal rows (all levels 0..15): row-major Zrow; leaves: Xbf.
__global__ __launch_bounds__(256) void cvt_all(
    const float* __restrict__ x, u16* __restrict__ Zrow,
    u16* __restrict__ Xbf)
{
    int idx = blockIdx.x * 256 + threadIdx.x;
    if (idx >= 131071 * 32) return;
    int row = idx >> 5, k8 = idx & 31;
    const float* s = x + (size_t)row * 256 + k8 * 8;
    u16 r[8];
#pragma unroll
    for (int i = 0; i < 8; i++) r[i] = f2bf(s[i]);
    if (row < 65535) {
        int d = 31 - __clz(row + 1);
        int jn = row - ((1 << d) - 1);
        *(uint4*)(Zrow + zrowOff(d) + (size_t)jn * 512 + k8 * 8) = *(uint4*)r;
    } else {
        int jn = row - 65535;
        *(uint4*)(Xbf + (size_t)jn * 256 + k8 * 8) = *(uint4*)r;
    }
}

// ---------------- stage 1a: big-level GEMM (256x256, dbuf 2-phase) --------
template<int KD, int NC>
__global__ __launch_bounds__(512, 2) void gate_gemm_big(
    const u16* __restrict__ A, const u16* __restrict__ B,
    const float* __restrict__ bias, _Float16* __restrict__ G)
{
    constexpr int NT = KD / 64;
    extern __shared__ u16 S[];           // [2][A:16384 | B:16384]

    const int tid  = threadIdx.x;
    const int wave = tid >> 6;
    const int lane = tid & 63;
    const int bm = blockIdx.x * 256;
    const int bn = blockIdx.y * 256;

    const int srow = lane >> 3;
    const int scol = ((lane & 7) ^ srow) * 8;

    const int wr = wave >> 2;
    const int wc = wave & 3;
    const int lm = lane & 15, q4 = lane >> 4;

    auto stage = [&](int bi, int t) {
#pragma unroll
        for (int q = 0; q < 4; ++q) {
            const int g = wave * 4 + q;
            const int r = g * 8 + srow;
            gld_lds16(A + (size_t)(bm + r) * KD + t * 64 + scol,
                      S + bi * 32768 + g * 512 + lane * 8);
            gld_lds16(B + (size_t)(bn + r) * KD + t * 64 + scol,
                      S + bi * 32768 + 16384 + g * 512 + lane * 8);
        }
    };

    f32x4 acc[8][4] = {};

    stage(0, 0);
    __syncthreads();

#pragma unroll
    for (int t = 0; t < NT; ++t) {
        if (t + 1 < NT) stage((t + 1) & 1, t + 1);

        const u16* Ab = S + (t & 1) * 32768;
        const u16* Bb = Ab + 16384;
#pragma unroll
        for (int kk = 0; kk < 64; kk += 32) {
            const int sw = ((((kk >> 3) + q4) ^ (lm & 7)) << 3);
            bf16x8 af[8], bfr[4];
#pragma unroll
            for (int i = 0; i < 8; i++)
                af[i] = *(const bf16x8*)(Ab + (wr * 128 + i * 16 + lm) * 64 + sw);
#pragma unroll
            for (int j = 0; j < 4; j++)
                bfr[j] = *(const bf16x8*)(Bb + (wc * 64 + j * 16 + lm) * 64 + sw);
#pragma unroll
            for (int i = 0; i < 8; i++)
#pragma unroll
                for (int j = 0; j < 4; j++)
                    acc[i][j] = __builtin_amdgcn_mfma_f32_16x16x32_bf16(
                        af[i], bfr[j], acc[i][j], 0, 0, 0);
        }
        __syncthreads();
    }

    const int cr0 = q4 * 4;
#pragma unroll
    for (int i = 0; i < 8; i++) {
#pragma unroll
        for (int j = 0; j < 4; j++) {
            const int cg = bn + wc * 64 + j * 16 + lm;
            const float bb = bias[cg];
            const bool istan = ((cg >> 8) == 2);
#pragma unroll
            for (int reg = 0; reg < 4; reg++) {
                const int rr = bm + wr * 128 + i * 16 + cr0 + reg;
                float v = acc[i][j][reg] + bb;
                G[(size_t)rr * NC + cg] =
                    (_Float16)(istan ? fast_tanh(v) : fast_sig(v));
            }
        }
    }
}

// ---------------- stage 1b: 128x128 gate GEMM (d=12) -----------
__global__ __launch_bounds__(256) void gate_gemm(
    const u16* __restrict__ A, int lda, int M,
    const u16* __restrict__ B, int ldb, int Kdim,
    const float* __restrict__ bias, _Float16* __restrict__ G, int NC)
{
    __shared__ u16 As[128 * 64];
    __shared__ u16 Bs[128 * 64];

    const int tid  = threadIdx.x;
    const int wave = tid >> 6;
    const int lane = tid & 63;
    const int bm = blockIdx.x * 128;
    const int bn = blockIdx.y * 128;

    const int wm = (wave >> 1) * 64;
    const int wn = (wave & 1) * 64;
    const int lm = lane & 15;
    const int q4 = lane >> 4;

    const int srow = lane >> 3;
    const int scol = ((lane & 7) ^ srow) * 8;

    f32x4 acc[4][4] = {};

    for (int k0 = 0; k0 < Kdim; k0 += 64) {
#pragma unroll
        for (int q = 0; q < 4; ++q) {
            const int grp = wave * 4 + q;
            const int r = grp * 8 + srow;
            gld_lds16(A + (size_t)(bm + r) * lda + k0 + scol,
                      As + (size_t)grp * 512 + lane * 8);
            gld_lds16(B + (size_t)(bn + r) * ldb + k0 + scol,
                      Bs + (size_t)grp * 512 + lane * 8);
        }
        __syncthreads();

#pragma unroll
        for (int kk = 0; kk < 64; kk += 32) {
            const int sw = (((kk >> 3) + q4) ^ (lm & 7)) << 3;
            bf16x8 af[4], bfr[4];
#pragma unroll
            for (int i = 0; i < 4; i++)
                af[i] = *(const bf16x8*)(As + (wm + i * 16 + lm) * 64 + sw);
#pragma unroll
            for (int j = 0; j < 4; j++)
                bfr[j] = *(const bf16x8*)(Bs + (wn + j * 16 + lm) * 64 + sw);
#pragma unroll
            for (int i = 0; i < 4; i++)
#pragma unroll
                for (int j = 0; j < 4; j++)
                    acc[i][j] = __builtin_amdgcn_mfma_f32_16x16x32_bf16(
                        af[i], bfr[j], acc[i][j], 0, 0, 0);
        }
        __syncthreads();
    }

    const int cr0 = q4 * 4;
    const int ccc = lm;
#pragma unroll
    for (int i = 0; i < 4; i++) {
#pragma unroll
        for (int reg = 0; reg < 4; reg++) {
            int r = bm + wm + i * 16 + cr0 + reg;
            if (r >= M) continue;
#pragma unroll
            for (int j = 0; j < 4; j++) {
                int cn = bn + wn + j * 16 + ccc;
                float v = acc[i][j][reg] + bias[cn];
                float a = ((cn >> 8) == 2) ? fast_tanh(v) : fast_sig(v);
                G[(size_t)r * NC + cn] = (_Float16)a;
            }
        }
    }
}

// ---------------- stage 2: vectorized combine (z row-major) --------
template<bool LEAF>
__global__ __launch_bounds__(256) void combine_v(
    const _Float16* __restrict__ G, const float* __restrict__ csrc,
    float* __restrict__ cdst, u16* __restrict__ zrow_parent)
{
    constexpr int NC = LEAF ? 768 : 1280;
    const int t  = threadIdx.x;
    const int p  = blockIdx.x * 8 + (t >> 5);      // global pair index
    const int h0 = (t & 31) * 8;

    const _Float16* G0 = G + (size_t)(2 * p) * NC + h0;
    const _Float16* G1 = G0 + NC;

    f16x8 i0 = *(const f16x8*)(G0);
    f16x8 o0 = *(const f16x8*)(G0 + 256);
    f16x8 u0 = *(const f16x8*)(G0 + 512);
    f16x8 i1 = *(const f16x8*)(G1);
    f16x8 o1 = *(const f16x8*)(G1 + 256);
    f16x8 u1 = *(const f16x8*)(G1 + 512);

    f32x8 c0, c1;
#pragma unroll
    for (int e = 0; e < 8; e++) {
        c0[e] = (float)i0[e] * (float)u0[e];
        c1[e] = (float)i1[e] * (float)u1[e];
    }
    if (!LEAF) {
        f16x8 f00 = *(const f16x8*)(G0 + 768);
        f16x8 f10 = *(const f16x8*)(G0 + 1024);
        f16x8 f01 = *(const f16x8*)(G1 + 768);
        f16x8 f11 = *(const f16x8*)(G1 + 1024);
        const float* cs = csrc + (size_t)(4 * p) * 256 + h0;
        f32x8 cc0 = *(const f32x8*)(cs);
        f32x8 cc1 = *(const f32x8*)(cs + 256);
        f32x8 cc2 = *(const f32x8*)(cs + 512);
        f32x8 cc3 = *(const f32x8*)(cs + 768);
#pragma unroll
        for (int e = 0; e < 8; e++) {
            c0[e] += (float)f00[e] * cc0[e] + (float)f10[e] * cc1[e];
            c1[e] += (float)f01[e] * cc2[e] + (float)f11[e] * cc3[e];
        }
    }

    u16 hs[8];
#pragma unroll
    for (int e = 0; e < 8; e++) {
        float h0v = (float)o0[e] * fast_tanh(c0[e]);
        float h1v = (float)o1[e] * fast_tanh(c1[e]);
        hs[e] = f2bf(h0v + h1v);
    }

    float* cd = cdst + (size_t)(2 * p) * 256 + h0;
    *(f32x8*)(cd) = c0;
    *(f32x8*)(cd + 256) = c1;

    *(uint4*)(zrow_parent + (size_t)p * 512 + 256 + h0) = *(uint4*)hs;
}

// ---------------- persistent lower-tree kernel (d=11..0) ----------------
// 80 blocks x 256 thr (co-resident), no LDS. Per level:
//   gemm phase: wave-units of 16 rows x 4 col-tiles (64KB Wfrag slice, L2-hot)
//               -> pre[row][1280] (= acc + bias)
//   grid barrier
//   epilogue:   vectorized combine (pairs) -> cdst, parent z; root -> out
//   grid barrier
__global__ __launch_bounds__(256, 1) void lower_levels(
    u16* __restrict__ Zrow, const u16* __restrict__ Wfrag,
    const float* __restrict__ bbig, float* __restrict__ cA,
    float* __restrict__ cB, float* __restrict__ pre,
    float* __restrict__ out, unsigned* __restrict__ cnt)
{
    const int tid  = threadIdx.x;
    const int lane = tid & 63;
    const int gw   = blockIdx.x * 4 + (tid >> 6);     // 0..319
    const int gt   = blockIdx.x * 256 + tid;          // 0..20479
    const int cc = lane & 15, rq = (lane >> 4) * 4;
    unsigned ph = 0;

    for (int d = 11; d >= 0; --d) {
        const int n = 1 << d;
        const u16* Z = Zrow + zrowOff(d);
        const int rgc = (n + 15) >> 4;

        // ---- gemm phase ----
        for (int u = gw; u < rgc * 20; u += NBLK * 4) {
            const int rgI = u / 20;
            const int q   = u - rgI * 20;
            const int nt0 = (q >> 2) * 16 + (q & 3) * 4;
            int rowA = rgI * 16 + cc; if (rowA >= n) rowA = n - 1;
            const u16* aB = Z + (size_t)rowA * 512 + (lane >> 4) * 8;
            const u16* bB = Wfrag + ((size_t)nt0 * 16 * 64 + lane) * 8;
            f32x4 acc[4] = {};
#pragma unroll
            for (int kc = 0; kc < 16; ++kc) {
                bf16x8 aX = *(const bf16x8*)(aB + kc * 32);
#pragma unroll
                for (int j = 0; j < 4; ++j) {
                    bf16x8 bX = *(const bf16x8*)(bB + (size_t)(j * 16 + kc) * 512);
                    acc[j] = __builtin_amdgcn_mfma_f32_16x16x32_bf16(
                        aX, bX, acc[j], 0, 0, 0);
                }
            }
#pragma unroll
            for (int j = 0; j < 4; ++j) {
                const int coln = (nt0 + j) * 16 + cc;
                const float bb = bbig[coln];
#pragma unroll
                for (int r = 0; r < 4; ++r) {
                    const int row = rgI * 16 + rq + r;
                    if (row < n) pre[(size_t)row * 1280 + coln] = acc[j][r] + bb;
                }
            }
        }
        gbar(cnt, ph);

        const float* csrc = (d & 1) ? cA : cB;
        float* cdst       = (d & 1) ? cB : cA;

        // ---- epilogue phase ----
        if (d == 0) {
            if (gt < 32) {
                const int h0 = gt * 8;
                const float* p = pre + h0;
                f32x8 iv = *(const f32x8*)(p);
                f32x8 ov = *(const f32x8*)(p + 256);
                f32x8 uv = *(const f32x8*)(p + 512);
                f32x8 f0 = *(const f32x8*)(p + 768);
                f32x8 f1 = *(const f32x8*)(p + 1024);
                f32x8 cs0 = *(const f32x8*)(csrc + h0);
                f32x8 cs1 = *(const f32x8*)(csrc + 256 + h0);
#pragma unroll
                for (int e = 0; e < 8; e++) {
                    float c = fast_sig(iv[e]) * fast_tanh(uv[e])
                            + fast_sig(f0[e]) * cs0[e]
                            + fast_sig(f1[e]) * cs1[e];
                    out[h0 + e] = fast_sig(ov[e]) * fast_tanh(c);
                    out[256 + h0 + e] = c;
                }
            }
            // last level: no trailing barrier needed
        } else {
            u16* zp = Zrow + zrowOff(d - 1);
            const int items = (n >> 1) * 32;
            for (int it = gt; it < items; it += NBLK * 256) {
                const int pI = it >> 5;
                const int h0 = (it & 31) * 8;
                const float* p0 = pre + (size_t)(2 * pI) * 1280 + h0;
                const float* p1 = p0 + 1280;
                const float* cs = csrc + (size_t)(4 * pI) * 256 + h0;
                f32x8 i0 = *(const f32x8*)(p0);
                f32x8 o0 = *(const f32x8*)(p0 + 256);
                f32x8 u0 = *(const f32x8*)(p0 + 512);
                f32x8 f00 = *(const f32x8*)(p0 + 768);
                f32x8 f10 = *(const f32x8*)(p0 + 1024);
                f32x8 i1 = *(const f32x8*)(p1);
                f32x8 o1 = *(const f32x8*)(p1 + 256);
                f32x8 u1 = *(const f32x8*)(p1 + 512);
                f32x8 f01 = *(const f32x8*)(p1 + 768);
                f32x8 f11 = *(const f32x8*)(p1 + 1024);
                f32x8 cc0 = *(const f32x8*)(cs);
                f32x8 cc1 = *(const f32x8*)(cs + 256);
                f32x8 cc2 = *(const f32x8*)(cs + 512);
                f32x8 cc3 = *(const f32x8*)(cs + 768);
                f32x8 c0v, c1v;
                u16 hs[8];
#pragma unroll
                for (int e = 0; e < 8; e++) {
                    c0v[e] = fast_sig(i0[e]) * fast_tanh(u0[e])
                           + fast_sig(f00[e]) * cc0[e]
                           + fast_sig(f10[e]) * cc1[e];
                    c1v[e] = fast_sig(i1[e]) * fast_tanh(u1[e])
                           + fast_sig(f01[e]) * cc2[e]
                           + fast_sig(f11[e]) * cc3[e];
                    float h0v = fast_sig(o0[e]) * fast_tanh(c0v[e]);
                    float h1v = fast_sig(o1[e]) * fast_tanh(c1v[e]);
                    hs[e] = f2bf(h0v + h1v);
                }
                float* cd = cdst + (size_t)(2 * pI) * 256 + h0;
                *(f32x8*)(cd) = c0v;
                *(f32x8*)(cd + 256) = c1v;
                *(uint4*)(zp + (size_t)pI * 512 + 256 + h0) = *(uint4*)hs;
            }
            gbar(cnt, ph);
        }
    }
}

// ---------------- launch ----------------
extern "C" void kernel_launch(void* const* d_in, const int* in_sizes, int n_in,
                              void* d_out, int out_size, void* d_ws, size_t ws_size,
                              hipStream_t stream)
{
    const float* x   = (const float*)d_in[0];
    const float* Wi  = (const float*)d_in[1];
    const float* bi  = (const float*)d_in[2];
    const float* Wf  = (const float*)d_in[3];
    const float* bf  = (const float*)d_in[4];
    const float* Wo  = (const float*)d_in[5];
    const float* bo  = (const float*)d_in[6];
    const float* Wu  = (const float*)d_in[7];
    const float* bu  = (const float*)d_in[8];
    const float* Ui  = (const float*)d_in[9];
    const float* Uo  = (const float*)d_in[10];
    const float* Uu  = (const float*)d_in[11];
    const float* Wfk = (const float*)d_in[12];
    float* out = (float*)d_out;
    char* ws   = (char*)d_ws;
    (void)ws_size; (void)in_sizes; (void)n_in; (void)out_size;

    size_t off = 0;
    u16* Wrow     = (u16*)(ws + off); off += (size_t)1280 * 512 * 2;
    u16* Wfrag    = (u16*)(ws + off); off += (size_t)1280 * 512 * 2;
    u16* WleafRow = (u16*)(ws + off); off += (size_t)768 * 256 * 2;
    float* bbig   = (float*)(ws + off); off += 1280 * 4;
    float* bleaf  = (float*)(ws + off); off += 768 * 4;
    unsigned* barcnt = (unsigned*)(ws + off); off += 256;                    // align
    u16* Xbf    = (u16*)(ws + off); off += (size_t)65536 * 256 * 2;          // 32 MB
    u16* Zrow   = (u16*)(ws + off); off += (size_t)65536 * 512 * 2;          // 64 MB
    float* cA = (float*)(ws + off); off += (size_t)65536 * 256 * 4;          // 64 MB
    float* cB = (float*)(ws + off); off += (size_t)32768 * 256 * 4;          // 32 MB
    float* pre = (float*)(ws + off); off += (size_t)2048 * 1280 * 4;         // 10.5 MB
    _Float16* Ghalf = (_Float16*)(ws + off); off += (size_t)65536 * 768 * 2; // 96 MB

    // allow 128KB dynamic LDS for the big gemm (host-side, idempotent)
    static bool attr_set = false;
    if (!attr_set) {
        hipFuncSetAttribute((const void*)gate_gemm_big<512, 1280>,
                            hipFuncAttributeMaxDynamicSharedMemorySize, 131072);
        hipFuncSetAttribute((const void*)gate_gemm_big<256, 768>,
                            hipFuncAttributeMaxDynamicSharedMemorySize, 131072);
        attr_set = true;
    }

    // 1) pack weights (+ reset barrier counter) + convert x
    pack_weights<<<5897, 256, 0, stream>>>(Wi, bi, Wf, bf, Wo, bo, Wu, bu,
                                           Ui, Uo, Uu, Wfk, Wrow, Wfrag, WleafRow,
                                           bbig, bleaf, barcnt);
    cvt_all<<<16385, 256, 0, stream>>>(x, Zrow, Xbf);

    // 2) leaf: gemm (i,o,u fp16) + combine -> cA, Hs into Zrow level 15
    gate_gemm_big<256, 768><<<dim3(LEAF_N / 256, 3), 512, 131072, stream>>>(
        Xbf, WleafRow, bleaf, Ghalf);
    combine_v<true><<<LEAF_N / 16, 256, 0, stream>>>(
        Ghalf, nullptr, cA, Zrow + zrowOff(15));

    // 3) big internal levels d=15..12
    for (int d = 15; d >= 12; d--) {
        int n = 1 << d;
        float* csrc = (d & 1) ? cA : cB;
        float* cdst = (d & 1) ? cB : cA;
        if (d >= 13) {
            gate_gemm_big<512, 1280><<<dim3(n / 256, 5), 512, 131072, stream>>>(
                Zrow + zrowOff(d), Wrow, bbig, Ghalf);
        } else {
            gate_gemm<<<dim3(n / 128, 10), 256, 0, stream>>>(
                Zrow + zrowOff(d), 512, n, Wrow, 512, 512, bbig, Ghalf, 1280);
        }
        combine_v<false><<<n / 16, 256, 0, stream>>>(
            Ghalf, csrc, cdst, Zrow + zrowOff(d - 1));
    }

    // 4) persistent lower tree: d=11..0 (root writes out)
    lower_levels<<<NBLK, 256, 0, stream>>>(
        Zrow, Wfrag, bbig, cA, cB, pre, out, barcnt);
}